// Round 6
// baseline (805.274 us; speedup 1.0000x reference)
//
#include <hip/hip_runtime.h>

// DEQ MLP, B=1024, D_IN=512, D_H=1024, D_OUT=512. ALL I/O fp32.
// R17: PERSISTENT ROW-STRIPE KERNEL. Key insight: the Picard iteration
// z_{t+1}[i,:] = relu(z_t[i,:]@W1+b1)@W2+b2 is ROW-INDEPENDENT -- no
// cross-row (hence no cross-block) dependency exists in the entire solve.
// One kernel, 64 blocks x 512 threads; block owns a 16-row stripe whose
// activations live in LDS (2 x 32KB buffers) for the whole solve.
// Weights are read k-major directly from global (L2-resident across all
// iterations, since the kernel never ends -> no kernel-boundary L2
// invalidation). 2 dispatches total (prep + solve), 14 __syncthreads.
// Per-element accumulation order (k-ascending 16x16x32 MFMA) identical to
// R16 -> bitwise-same output. absmax expected exactly 2.441406e-4.

typedef _Float16 f16x8 __attribute__((ext_vector_type(8)));
typedef float    f32x4 __attribute__((ext_vector_type(4)));

// ---- LDS activation layout: [16 rows][1024 k] fp16, pitch 1024 (2KB/row).
// 16B chunks XOR-swizzled within each 16-chunk (256B) group:
//   gs = (g & ~15) | ((g & 15) ^ row)          (involution, bijective)
// Read (lane l15 = row, quad = k-subchunk): 16 lanes hit 16 distinct chunk
// slots -> 2 lanes per 4-bank group on ds_read_b128 = conflict-free (m136).

__device__ __forceinline__ f16x8 lda(const _Float16* s, int l15, int quad, int kc) {
  const int g  = kc * 4 + quad;
  const int gs = (g & ~15) | ((g & 15) ^ l15);
  return *(const f16x8*)(s + l15 * 1024 + gs * 8);
}

// One stripe-GEMM: out[16 x NF*16*8waves] = act(srcLDS[16 x K] @ WT^T + bias).
// Wave w handles cols [col0, col0 + 16*NF). B-frags straight from global WT
// (k-major [N][K]): per instr 16 rows x 32k touches 16 cachelines, fully
// consumed within an unroll-4 body (line = 64k = 2 kc) -> L1/L2-served.
template<int NF, int K, bool RELU, bool TOLDS>
__device__ __forceinline__ void gemm_stripe(
    const _Float16* __restrict__ src,     // LDS, swizzled
    _Float16* __restrict__ dstl,          // LDS, swizzled (if TOLDS)
    float* __restrict__ dstg, int dstN,   // global fp32 (if !TOLDS)
    const _Float16* __restrict__ WT,      // [N][K] fp16 k-major
    const float* __restrict__ bias,
    int col0, int l15, int quad, int r0out)
{
  f32x4 acc[NF];
  #pragma unroll
  for (int j = 0; j < NF; j++) { f32x4 z{0.f, 0.f, 0.f, 0.f}; acc[j] = z; }

  int boff[NF];                            // fp16-unit offsets, 32-bit
  #pragma unroll
  for (int j = 0; j < NF; j++) boff[j] = (col0 + 16 * j + l15) * K + quad * 8;

  constexpr int NK = K / 32;
  #pragma unroll 4
  for (int kc = 0; kc < NK; ++kc) {
    const f16x8 a = lda(src, l15, quad, kc);
    f16x8 b[NF];
    #pragma unroll
    for (int j = 0; j < NF; j++)
      b[j] = *(const f16x8*)(WT + boff[j] + kc * 32);
    #pragma unroll
    for (int j = 0; j < NF; j++)
      acc[j] = __builtin_amdgcn_mfma_f32_16x16x32_f16(a, b[j], acc[j], 0, 0, 0);
  }

  // Epilogue. C/D layout (m89-verified): col(N) = lane&15, row(M) = quad*4+r.
  #pragma unroll
  for (int j = 0; j < NF; j++) {
    const int col = col0 + 16 * j + l15;
    const float bb = bias[col];
    #pragma unroll
    for (int r = 0; r < 4; r++) {
      const int row = quad * 4 + r;
      float v = acc[j][r] + bb;
      if (RELU) v = fmaxf(v, 0.f);
      if (TOLDS) {
        const int g  = col >> 3;
        const int gs = (g & ~15) | ((g & 15) ^ row);
        dstl[row * 1024 + gs * 8 + (col & 7)] = (_Float16)v;
      } else {
        dstg[(size_t)(r0out + row) * dstN + col] = v;
      }
    }
  }
}

__global__ __launch_bounds__(512, 1)
void deq_stripe(const float* __restrict__ x,
                const _Float16* __restrict__ WinT,
                const _Float16* __restrict__ W1T,
                const _Float16* __restrict__ W2T,
                const _Float16* __restrict__ WoutT,
                const float* __restrict__ b_in,
                const float* __restrict__ b1,
                const float* __restrict__ b2,
                const float* __restrict__ b_out,
                float* __restrict__ out)
{
  __shared__ alignas(16) _Float16 zA[16 * 1024];   // 32 KB
  __shared__ alignas(16) _Float16 zB[16 * 1024];   // 32 KB
  const int tid  = threadIdx.x;
  const int w    = tid >> 6;
  const int lane = tid & 63;
  const int quad = lane >> 4;
  const int l15  = lane & 15;
  const int r0   = blockIdx.x * 16;                // stripe rows [r0, r0+16)

  // Stage x stripe (16 x 512 fp32) -> zB fp16, swizzled. 2048 float4 / 512 thr.
  #pragma unroll
  for (int i = 0; i < 4; ++i) {
    const int idx = i * 512 + tid;                 // 0..2047
    const int row = idx >> 7;                      // 0..15
    const int k0  = (idx & 127) * 4;               // 0..508
    const float4 v = *(const float4*)(x + (size_t)(r0 + row) * 512 + k0);
    const float f4[4] = {v.x, v.y, v.z, v.w};
    #pragma unroll
    for (int e = 0; e < 4; ++e) {
      const int k  = k0 + e;
      const int g  = k >> 3;
      const int gs = (g & ~15) | ((g & 15) ^ row);
      zB[row * 1024 + gs * 8 + (k & 7)] = (_Float16)f4[e];
    }
  }
  __syncthreads();

  const int c8 = w * 128;                          // wave cols, N=1024 GEMMs
  const int c4 = w * 64;                           // wave cols, N=512 out-proj

  // z0 = x @ W_in + b_in   (K=512) : zB -> zA
  gemm_stripe<8, 512, false, true>(zB, zA, nullptr, 0, WinT, b_in, c8, l15, quad, 0);
  __syncthreads();

  // Picard: z <- relu(z@W1+b1)@W2+b2, 6 iterations, all in LDS
  #pragma unroll 1
  for (int it = 0; it < 6; ++it) {
    gemm_stripe<8, 1024, true,  true>(zA, zB, nullptr, 0, W1T, b1, c8, l15, quad, 0);
    __syncthreads();
    gemm_stripe<8, 1024, false, true>(zB, zA, nullptr, 0, W2T, b2, c8, l15, quad, 0);
    __syncthreads();
  }

  // out = z* @ W_out + b_out (fp32, global)
  gemm_stripe<4, 1024, false, false>(zA, nullptr, out, 512, WoutT, b_out, c4, l15, quad, r0);
}

// Prep: 32x32 transpose+cvt tiles for W_in / W1 / W2 / W_out (3072 blocks).
__global__ __launch_bounds__(256)
void prep_all(const float* __restrict__ W_in,  _Float16* __restrict__ WinT,
              const float* __restrict__ W1,    _Float16* __restrict__ W1T,
              const float* __restrict__ W2,    _Float16* __restrict__ W2T,
              const float* __restrict__ W_out, _Float16* __restrict__ WoutT)
{
  int b = blockIdx.x;
  const float* src; _Float16* dst; int R, C, bx, by;
  if (b < 512)       {            src = W_in;  dst = WinT;  R = 512;  C = 1024; bx = b & 31; by = b >> 5; }
  else if (b < 1536) { b -= 512;  src = W1;    dst = W1T;   R = 1024; C = 1024; bx = b & 31; by = b >> 5; }
  else if (b < 2560) { b -= 1536; src = W2;    dst = W2T;   R = 1024; C = 1024; bx = b & 31; by = b >> 5; }
  else               { b -= 2560; src = W_out; dst = WoutT; R = 1024; C = 512;  bx = b & 15; by = b >> 4; }

  __shared__ float t[32][33];
  const int tx = threadIdx.x & 31;
  const int ty = threadIdx.x >> 5;
  const int c0 = bx * 32;
  const int r0 = by * 32;
  #pragma unroll
  for (int i = 0; i < 32; i += 8)
    t[ty + i][tx] = src[(size_t)(r0 + ty + i) * C + c0 + tx];
  __syncthreads();
  #pragma unroll
  for (int i = 0; i < 32; i += 8)
    dst[(size_t)(c0 + ty + i) * R + r0 + tx] = (_Float16)t[tx][ty + i];
}

extern "C" void kernel_launch(void* const* d_in, const int* in_sizes, int n_in,
                              void* d_out, int out_size, void* d_ws, size_t ws_size,
                              hipStream_t stream) {
  (void)in_sizes; (void)n_in; (void)out_size; (void)ws_size;
  const float* x     = (const float*)d_in[0];
  const float* W_in  = (const float*)d_in[1];
  const float* b_in  = (const float*)d_in[2];
  const float* W1    = (const float*)d_in[3];
  const float* b1    = (const float*)d_in[4];
  const float* W2    = (const float*)d_in[5];
  const float* b2    = (const float*)d_in[6];
  const float* W_out = (const float*)d_in[7];
  const float* b_out = (const float*)d_in[8];
  float* out = (float*)d_out;

  char* p = (char*)d_ws;
  _Float16* WinT  = (_Float16*)p; p += (size_t)1024 * 512 * 2;
  _Float16* W1T   = (_Float16*)p; p += (size_t)1024 * 1024 * 2;
  _Float16* W2T   = (_Float16*)p; p += (size_t)1024 * 1024 * 2;
  _Float16* WoutT = (_Float16*)p; p += (size_t)512 * 1024 * 2;

  prep_all<<<dim3(3072), dim3(256), 0, stream>>>(W_in, WinT, W1, W1T,
                                                 W2, W2T, W_out, WoutT);

  deq_stripe<<<dim3(64), dim3(512), 0, stream>>>(
      x, WinT, W1T, W2T, WoutT, b_in, b1, b2, b_out, out);
}

// Round 7
// 209.093 us; speedup vs baseline: 3.8513x; 3.8513x over previous
//
#include <hip/hip_runtime.h>

// DEQ MLP, B=1024, D_IN=512, D_H=1024, D_OUT=512. ALL I/O fp32.
// R18: 128x64 tiles, 8 waves (512 thr), 128 blocks, BK=128, 3-buffer
// gld_lds pipeline with counted vmcnt(6), ONE barrier per K-iter (R16
// skeleton). Halves staged traffic vs R16 (96->48 MB per K=1024 GEMM)
// while keeping 2 waves/SIMD for latency overlap. XCD-affinity mapping:
// bm = (blk&7)*128 puts all 16 same-m blocks on one XCD (round-robin
// dispatch) -> A-tile L2-amplified x16, distinct-from-L3 = 2MB; activation
// stripe j written and re-read by XCD j across layers. k-ascending MFMA
// order preserved -> bitwise-same output (absmax 2.441406e-4).

typedef _Float16 f16x8 __attribute__((ext_vector_type(8)));
typedef _Float16 f16x4v __attribute__((ext_vector_type(4)));
typedef float    f32x4 __attribute__((ext_vector_type(4)));

#define B_SZ 1024
#define DH   1024

#define GLD16(gp, lp) __builtin_amdgcn_global_load_lds(                        \
    (const __attribute__((address_space(1))) void*)(gp),                       \
    (__attribute__((address_space(3))) void*)(lp), 16, 0, 0)

// out[1024,N] = act(A[1024,K] (fp16) * Bt[N,K]^T (fp16) + bias).
// 128x64 tile, BK=128, 8 waves each 32x32 (2x2 16x16 frags). NITER = K/128.
// LDS rows 128 fp16 (256B = 16 chunks); both-sides involution swizzle:
// LDS (row, pos) holds global chunk pos ^ (row & 15).
template<bool RELU, bool OUTF32, int NITER>
__global__ __launch_bounds__(512, 1)
void gemm_big(const _Float16* __restrict__ A,
              const _Float16* __restrict__ Bt,
              const float* __restrict__ bias,
              _Float16* __restrict__ o16,
              float* __restrict__ o32,
              int N, int K)
{
  __shared__ alignas(16) _Float16 As[3][128 * 128];  // 3 x 32 KB
  __shared__ alignas(16) _Float16 Bs[3][64 * 128];   // 3 x 16 KB
  const int tid  = threadIdx.x;
  const int blk  = blockIdx.x;
  const int bm   = (blk & 7) * 128;    // XCD-affinity: m-stripe = blk % 8
  const int bn   = (blk >> 3) * 64;
  const int w    = tid >> 6;           // 0..7
  const int lane = tid & 63;
  const int quad = lane >> 4;
  const int l15  = lane & 15;
  const int wr   = (w >> 1) * 32;      // wave rows [wr, wr+32)
  const int wc   = (w & 1) * 32;       // wave cols [wc, wc+32)
  const int lr   = lane >> 4;          // 0..3: row within 4-row store segment
  const int lc   = lane & 15;          // 0..15: chunk within 256B row

  // Staging per BK=128 chunk: A 128x128 fp16 = 32KB = 32 gld_lds (4/wave,
  // rows 16w+4j+lr); B 64x128 = 16KB = 16 gld_lds (2/wave, rows 8w+4j+lr).
  // Source chunk pre-swizzled by row&15 (involution, matches read side).
  const _Float16* gA[4];
  const _Float16* gB[2];
  #pragma unroll
  for (int j = 0; j < 4; j++) {
    const int row = 16 * w + 4 * j + lr;               // tile-local A row
    gA[j] = A + (size_t)(bm + row) * K + 8 * (lc ^ (row & 15));
  }
  #pragma unroll
  for (int j = 0; j < 2; j++) {
    const int row = 8 * w + 4 * j + lr;                // tile-local B row
    gB[j] = Bt + (size_t)(bn + row) * K + 8 * (lc ^ (row & 15));
  }

  f32x4 acc[2][2];
  #pragma unroll
  for (int i = 0; i < 2; i++)
    #pragma unroll
    for (int j = 0; j < 2; j++) { f32x4 z{0.f, 0.f, 0.f, 0.f}; acc[i][j] = z; }

  // issue one BK=128 chunk: 6 gld_lds per wave (A:4, B:2)
  #define ISSUE(b, c) do {                                                     \
    _Pragma("unroll")                                                          \
    for (int j = 0; j < 4; j++)                                                \
      GLD16(gA[j] + (size_t)(c) * 128, &As[(b)][(16 * w + 4 * j) * 128]);      \
    _Pragma("unroll")                                                          \
    for (int j = 0; j < 2; j++)                                                \
      GLD16(gB[j] + (size_t)(c) * 128, &Bs[(b)][(8 * w + 4 * j) * 128]);       \
  } while (0)

  // compute one BK=128 step from buffer `b` (swizzled ds_read, k ascending)
  #define COMPUTE(b) do {                                                      \
    f16x8 af[2][4], bf[2][4];                                                  \
    _Pragma("unroll")                                                          \
    for (int k = 0; k < 4; ++k) {                                              \
      const int c_ = ((4 * k + quad) ^ l15) * 8;                               \
      af[0][k] = *(const f16x8*)&As[(b)][(wr      + l15) * 128 + c_];          \
      af[1][k] = *(const f16x8*)&As[(b)][(wr + 16 + l15) * 128 + c_];          \
      bf[0][k] = *(const f16x8*)&Bs[(b)][(wc      + l15) * 128 + c_];          \
      bf[1][k] = *(const f16x8*)&Bs[(b)][(wc + 16 + l15) * 128 + c_];          \
    }                                                                          \
    _Pragma("unroll")                                                          \
    for (int k = 0; k < 4; ++k) {                                              \
      acc[0][0] = __builtin_amdgcn_mfma_f32_16x16x32_f16(af[0][k], bf[0][k], acc[0][0], 0, 0, 0); \
      acc[0][1] = __builtin_amdgcn_mfma_f32_16x16x32_f16(af[0][k], bf[1][k], acc[0][1], 0, 0, 0); \
      acc[1][0] = __builtin_amdgcn_mfma_f32_16x16x32_f16(af[1][k], bf[0][k], acc[1][0], 0, 0, 0); \
      acc[1][1] = __builtin_amdgcn_mfma_f32_16x16x32_f16(af[1][k], bf[1][k], acc[1][1], 0, 0, 0); \
    }                                                                          \
  } while (0)

  // Prologue: 2 chunks in flight (12 loads/wave outstanding).
  ISSUE(0, 0);
  ISSUE(1, 1);

  // Main loop: wait own chunk-it loads (vmcnt 6 = one newer chunk still in
  // flight), barrier, issue chunk it+2, compute chunk it.
  for (int it = 0; it < NITER - 2; ++it) {
    asm volatile("s_waitcnt vmcnt(6)" ::: "memory");
    __builtin_amdgcn_s_barrier();
    asm volatile("" ::: "memory");
    ISSUE((it + 2) % 3, it + 2);
    COMPUTE(it % 3);
  }
  // Tail: drain 6 -> 0.
  asm volatile("s_waitcnt vmcnt(6)" ::: "memory");
  __builtin_amdgcn_s_barrier();
  asm volatile("" ::: "memory");
  COMPUTE((NITER - 2) % 3);
  asm volatile("s_waitcnt vmcnt(0)" ::: "memory");
  __builtin_amdgcn_s_barrier();
  asm volatile("" ::: "memory");
  COMPUTE((NITER - 1) % 3);

  #undef ISSUE
  #undef COMPUTE

  // Epilogue: bias + act + store. C/D layout (m89-verified):
  // col = lane&15, row = quad*4 + reg
  #pragma unroll
  for (int n = 0; n < 2; n++) {
    const int col = bn + wc + n * 16 + l15;
    const float bb = bias[col];
    #pragma unroll
    for (int m = 0; m < 2; m++) {
      #pragma unroll
      for (int r = 0; r < 4; r++) {
        const int row = bm + wr + m * 16 + quad * 4 + r;
        float v = acc[m][n][r] + bb;
        if (RELU) v = fmaxf(v, 0.f);
        if (OUTF32) o32[(size_t)row * N + col] = v;
        else        o16[(size_t)row * N + col] = (_Float16)v;
      }
    }
  }
}

// One dispatch: x fp32->fp16 cvt (blocks 0..511), then 32x32 transpose+cvt
// tiles for W_in / W1 / W2 / W_out (blocks 512..3583).
__global__ __launch_bounds__(256)
void prep_all(const float* __restrict__ x,     _Float16* __restrict__ xh,
              const float* __restrict__ W_in,  _Float16* __restrict__ WinT,
              const float* __restrict__ W1,    _Float16* __restrict__ W1T,
              const float* __restrict__ W2,    _Float16* __restrict__ W2T,
              const float* __restrict__ W_out, _Float16* __restrict__ WoutT)
{
  int b = blockIdx.x;
  if (b < 512) {
    const int i = (b * 256 + threadIdx.x) * 4;          // 512*256*4 = 1024*512
    const float4 v = *(const float4*)(x + i);
    f16x4v hv{(_Float16)v.x, (_Float16)v.y, (_Float16)v.z, (_Float16)v.w};
    *(f16x4v*)(xh + i) = hv;
    return;
  }
  b -= 512;
  const float* src; _Float16* dst; int R, C, bx, by;
  if (b < 512)       { src = W_in;  dst = WinT;  R = 512;  C = 1024; bx = b & 31; by = b >> 5; }
  else if (b < 1536) { b -= 512;  src = W1;    dst = W1T;   R = 1024; C = 1024; bx = b & 31; by = b >> 5; }
  else if (b < 2560) { b -= 1536; src = W2;    dst = W2T;   R = 1024; C = 1024; bx = b & 31; by = b >> 5; }
  else               { b -= 2560; src = W_out; dst = WoutT; R = 1024; C = 512;  bx = b & 15; by = b >> 4; }

  __shared__ float t[32][33];
  const int tx = threadIdx.x & 31;
  const int ty = threadIdx.x >> 5;
  const int c0 = bx * 32;
  const int r0 = by * 32;
  #pragma unroll
  for (int i = 0; i < 32; i += 8)
    t[ty + i][tx] = src[(size_t)(r0 + ty + i) * C + c0 + tx];
  __syncthreads();
  #pragma unroll
  for (int i = 0; i < 32; i += 8)
    dst[(size_t)(c0 + ty + i) * R + r0 + tx] = (_Float16)t[tx][ty + i];
}

extern "C" void kernel_launch(void* const* d_in, const int* in_sizes, int n_in,
                              void* d_out, int out_size, void* d_ws, size_t ws_size,
                              hipStream_t stream) {
  (void)in_sizes; (void)n_in; (void)out_size; (void)ws_size;
  const float* x     = (const float*)d_in[0];
  const float* W_in  = (const float*)d_in[1];
  const float* b_in  = (const float*)d_in[2];
  const float* W1    = (const float*)d_in[3];
  const float* b1    = (const float*)d_in[4];
  const float* W2    = (const float*)d_in[5];
  const float* b2    = (const float*)d_in[6];
  const float* W_out = (const float*)d_in[7];
  const float* b_out = (const float*)d_in[8];
  float* out = (float*)d_out;

  const size_t BD = (size_t)B_SZ * DH;   // 1M
  char* p = (char*)d_ws;
  _Float16* xh    = (_Float16*)p; p += (size_t)1024 * 512 * 2;
  _Float16* WinT  = (_Float16*)p; p += (size_t)1024 * 512 * 2;
  _Float16* W1T   = (_Float16*)p; p += (size_t)DH * DH * 2;
  _Float16* W2T   = (_Float16*)p; p += (size_t)DH * DH * 2;
  _Float16* WoutT = (_Float16*)p; p += (size_t)512 * 1024 * 2;
  _Float16* za    = (_Float16*)p; p += BD * 2;
  _Float16* zb    = (_Float16*)p; p += BD * 2;
  _Float16* h     = (_Float16*)p; p += BD * 2;

  dim3 blk256(256);
  prep_all<<<dim3(3584), blk256, 0, stream>>>(x, xh, W_in, WinT, W1, W1T,
                                              W2, W2T, W_out, WoutT);

  dim3 blk512(512);
  // grid: blk = n*8 + m  (m-stripe = blk%8 -> XCD affinity)
  const dim3 g1024(128);           // 1024x1024 out: 8 m x 16 n tiles
  const dim3 g512 (64);            // 1024x512  out: 8 m x  8 n tiles

  // z0 = x @ W_in + b_in   (K=512 -> NITER=4)
  gemm_big<false, false, 4><<<g1024, blk512, 0, stream>>>(
      xh, WinT, b_in, za, nullptr, 1024, 512);

  // Picard: z <- relu(z@W1+b1)@W2+b2, 6 iterations (K=1024 -> NITER=8)
  _Float16* zc = za;
  _Float16* zn = zb;
  for (int it = 0; it < 6; it++) {
    gemm_big<true, false, 8><<<g1024, blk512, 0, stream>>>(
        zc, W1T, b1, h, nullptr, 1024, 1024);
    gemm_big<false, false, 8><<<g1024, blk512, 0, stream>>>(
        h, W2T, b2, zn, nullptr, 1024, 1024);
    _Float16* t = zc; zc = zn; zn = t;
  }

  // out = z* @ W_out + b_out (fp32)
  gemm_big<false, true, 8><<<g512, blk512, 0, stream>>>(
      zc, WoutT, b_out, nullptr, out, 512, 1024);
}

// Round 8
// 200.161 us; speedup vs baseline: 4.0231x; 1.0446x over previous
//
#include <hip/hip_runtime.h>

// DEQ MLP, B=1024, D_IN=512, D_H=1024, D_OUT=512. ALL I/O fp32.
// R19: (a) R18's per-CU-efficient fat-block regime on ALL 256 CUs:
// 64x64 tiles, 8 waves (512 thr), 256 blocks, BK=128, 3-buffer gld_lds
// pipeline, counted vmcnt(4), ONE barrier per K-iter. Per-GEMM staged
// traffic 64 MB, per-CU 256 KB. XCD-affinity: each XCD owns 2 m-stripes
// (unique 2.25 MB < 4 MB L2). (b) DIAGNOSTIC: one Picard GEMM runs with
// REPEAT=6 (recomputes the identical result; correctness preserved) so it
// surfaces above the 42us harness fills in rocprof top-5 -- first-ever
// clean counters for the hot loop. k-ascending MFMA order preserved ->
// bitwise-same output (absmax 2.441406e-4).

typedef _Float16 f16x8 __attribute__((ext_vector_type(8)));
typedef _Float16 f16x4v __attribute__((ext_vector_type(4)));
typedef float    f32x4 __attribute__((ext_vector_type(4)));

#define B_SZ 1024
#define DH   1024

#define GLD16(gp, lp) __builtin_amdgcn_global_load_lds(                        \
    (const __attribute__((address_space(1))) void*)(gp),                       \
    (__attribute__((address_space(3))) void*)(lp), 16, 0, 0)

// out[1024,N] = act(A[1024,K] (fp16) * Bt[N,K]^T (fp16) + bias).
// 64x64 tile, BK=128, 8 waves each 16x32 (1x2 16x16 frags). NITER = K/128.
// LDS rows 128 fp16 (256B = 16 chunks); both-sides involution swizzle:
// LDS (row, pos) holds global chunk pos ^ (row & 15).
template<bool RELU, bool OUTF32, int NITER, int REPEAT = 1>
__global__ __launch_bounds__(512, 1)
void gemm64(const _Float16* __restrict__ A,
            const _Float16* __restrict__ Bt,
            const float* __restrict__ bias,
            _Float16* __restrict__ o16,
            float* __restrict__ o32,
            int N, int K)
{
  __shared__ alignas(16) _Float16 As[3][64 * 128];   // 3 x 16 KB
  __shared__ alignas(16) _Float16 Bs[3][64 * 128];   // 3 x 16 KB
  const int tid  = threadIdx.x;
  const int blk  = blockIdx.x;
  // XCD-affinity: xcd = blk%8 (round-robin dispatch). Each XCD: 2 m-stripes,
  // all n -> unique footprint A 256KB + B 2MB = 2.25MB < 4MB L2.
  const int xcd  = blk & 7;
  const int q    = blk >> 3;
  const int bm   = (xcd * 2 + (q & 1)) * 64;
  const int bn   = (q >> 1) * 64;
  const int w    = tid >> 6;           // 0..7
  const int lane = tid & 63;
  const int quad = lane >> 4;
  const int l15  = lane & 15;
  const int wr   = (w >> 1) * 16;      // wave rows [wr, wr+16)
  const int wc   = (w & 1) * 32;       // wave cols [wc, wc+32)
  const int lr   = lane >> 4;          // 0..3: row within 4-row store segment
  const int lc   = lane & 15;          // 0..15: chunk within 256B row

  // Staging per BK=128 chunk: A 64x128 fp16 = 16KB = 16 gld_lds (2/wave,
  // rows 8w+4j+lr); B identical. Source chunk pre-swizzled by row&15.
  const _Float16* gA[2];
  const _Float16* gB[2];
  #pragma unroll
  for (int j = 0; j < 2; j++) {
    const int row = 8 * w + 4 * j + lr;                // tile-local row
    gA[j] = A  + (size_t)(bm + row) * K + 8 * (lc ^ (row & 15));
    gB[j] = Bt + (size_t)(bn + row) * K + 8 * (lc ^ (row & 15));
  }

  f32x4 acc[2];

  // issue one BK=128 chunk: 4 gld_lds per wave (A:2, B:2)
  #define ISSUE(b, c) do {                                                     \
    _Pragma("unroll")                                                          \
    for (int j = 0; j < 2; j++)                                                \
      GLD16(gA[j] + (size_t)(c) * 128, &As[(b)][(8 * w + 4 * j) * 128]);       \
    _Pragma("unroll")                                                          \
    for (int j = 0; j < 2; j++)                                                \
      GLD16(gB[j] + (size_t)(c) * 128, &Bs[(b)][(8 * w + 4 * j) * 128]);       \
  } while (0)

  // compute one BK=128 step from buffer `b` (swizzled ds_read, k ascending)
  #define COMPUTE(b) do {                                                      \
    f16x8 af[4], bf[2][4];                                                     \
    _Pragma("unroll")                                                          \
    for (int k = 0; k < 4; ++k) {                                              \
      const int c_ = ((4 * k + quad) ^ l15) * 8;                               \
      af[k]    = *(const f16x8*)&As[(b)][(wr      + l15) * 128 + c_];          \
      bf[0][k] = *(const f16x8*)&Bs[(b)][(wc      + l15) * 128 + c_];          \
      bf[1][k] = *(const f16x8*)&Bs[(b)][(wc + 16 + l15) * 128 + c_];          \
    }                                                                          \
    _Pragma("unroll")                                                          \
    for (int k = 0; k < 4; ++k) {                                              \
      acc[0] = __builtin_amdgcn_mfma_f32_16x16x32_f16(af[k], bf[0][k], acc[0], 0, 0, 0); \
      acc[1] = __builtin_amdgcn_mfma_f32_16x16x32_f16(af[k], bf[1][k], acc[1], 0, 0, 0); \
    }                                                                          \
  } while (0)

  #pragma unroll 1
  for (int rep = 0; rep < REPEAT; ++rep) {
    #pragma unroll
    for (int j = 0; j < 2; j++) { f32x4 z{0.f, 0.f, 0.f, 0.f}; acc[j] = z; }
    if (rep > 0) {                       // all waves done reading before reuse
      __builtin_amdgcn_s_barrier();
      asm volatile("" ::: "memory");
    }
    // Prologue: 2 chunks in flight (8 loads/wave outstanding).
    ISSUE(0, 0);
    ISSUE(1, 1);
    for (int it = 0; it < NITER - 2; ++it) {
      asm volatile("s_waitcnt vmcnt(4)" ::: "memory");
      __builtin_amdgcn_s_barrier();
      asm volatile("" ::: "memory");
      ISSUE((it + 2) % 3, it + 2);
      COMPUTE(it % 3);
    }
    asm volatile("s_waitcnt vmcnt(4)" ::: "memory");
    __builtin_amdgcn_s_barrier();
    asm volatile("" ::: "memory");
    COMPUTE((NITER - 2) % 3);
    asm volatile("s_waitcnt vmcnt(0)" ::: "memory");
    __builtin_amdgcn_s_barrier();
    asm volatile("" ::: "memory");
    COMPUTE((NITER - 1) % 3);
  }

  #undef ISSUE
  #undef COMPUTE

  // Epilogue: bias + act + store. C/D layout (m89-verified):
  // col = lane&15 (tracks B frag), row = quad*4 + reg (tracks A frag)
  #pragma unroll
  for (int j = 0; j < 2; j++) {
    const int col = bn + wc + j * 16 + l15;
    const float bb = bias[col];
    #pragma unroll
    for (int r = 0; r < 4; r++) {
      const int row = bm + wr + quad * 4 + r;
      float v = acc[j][r] + bb;
      if (RELU) v = fmaxf(v, 0.f);
      if (OUTF32) o32[(size_t)row * N + col] = v;
      else        o16[(size_t)row * N + col] = (_Float16)v;
    }
  }
}

// One dispatch: x fp32->fp16 cvt (blocks 0..511), then 32x32 transpose+cvt
// tiles for W_in / W1 / W2 / W_out (blocks 512..3583).
__global__ __launch_bounds__(256)
void prep_all(const float* __restrict__ x,     _Float16* __restrict__ xh,
              const float* __restrict__ W_in,  _Float16* __restrict__ WinT,
              const float* __restrict__ W1,    _Float16* __restrict__ W1T,
              const float* __restrict__ W2,    _Float16* __restrict__ W2T,
              const float* __restrict__ W_out, _Float16* __restrict__ WoutT)
{
  int b = blockIdx.x;
  if (b < 512) {
    const int i = (b * 256 + threadIdx.x) * 4;          // 512*256*4 = 1024*512
    const float4 v = *(const float4*)(x + i);
    f16x4v hv{(_Float16)v.x, (_Float16)v.y, (_Float16)v.z, (_Float16)v.w};
    *(f16x4v*)(xh + i) = hv;
    return;
  }
  b -= 512;
  const float* src; _Float16* dst; int R, C, bx, by;
  if (b < 512)       { src = W_in;  dst = WinT;  R = 512;  C = 1024; bx = b & 31; by = b >> 5; }
  else if (b < 1536) { b -= 512;  src = W1;    dst = W1T;   R = 1024; C = 1024; bx = b & 31; by = b >> 5; }
  else if (b < 2560) { b -= 1536; src = W2;    dst = W2T;   R = 1024; C = 1024; bx = b & 31; by = b >> 5; }
  else               { b -= 2560; src = W_out; dst = WoutT; R = 1024; C = 512;  bx = b & 15; by = b >> 4; }

  __shared__ float t[32][33];
  const int tx = threadIdx.x & 31;
  const int ty = threadIdx.x >> 5;
  const int c0 = bx * 32;
  const int r0 = by * 32;
  #pragma unroll
  for (int i = 0; i < 32; i += 8)
    t[ty + i][tx] = src[(size_t)(r0 + ty + i) * C + c0 + tx];
  __syncthreads();
  #pragma unroll
  for (int i = 0; i < 32; i += 8)
    dst[(size_t)(c0 + ty + i) * R + r0 + tx] = (_Float16)t[tx][ty + i];
}

extern "C" void kernel_launch(void* const* d_in, const int* in_sizes, int n_in,
                              void* d_out, int out_size, void* d_ws, size_t ws_size,
                              hipStream_t stream) {
  (void)in_sizes; (void)n_in; (void)out_size; (void)ws_size;
  const float* x     = (const float*)d_in[0];
  const float* W_in  = (const float*)d_in[1];
  const float* b_in  = (const float*)d_in[2];
  const float* W1    = (const float*)d_in[3];
  const float* b1    = (const float*)d_in[4];
  const float* W2    = (const float*)d_in[5];
  const float* b2    = (const float*)d_in[6];
  const float* W_out = (const float*)d_in[7];
  const float* b_out = (const float*)d_in[8];
  float* out = (float*)d_out;

  const size_t BD = (size_t)B_SZ * DH;   // 1M
  char* p = (char*)d_ws;
  _Float16* xh    = (_Float16*)p; p += (size_t)1024 * 512 * 2;
  _Float16* WinT  = (_Float16*)p; p += (size_t)1024 * 512 * 2;
  _Float16* W1T   = (_Float16*)p; p += (size_t)DH * DH * 2;
  _Float16* W2T   = (_Float16*)p; p += (size_t)DH * DH * 2;
  _Float16* WoutT = (_Float16*)p; p += (size_t)512 * 1024 * 2;
  _Float16* za    = (_Float16*)p; p += BD * 2;
  _Float16* zb    = (_Float16*)p; p += BD * 2;
  _Float16* h     = (_Float16*)p; p += BD * 2;

  dim3 blk256(256);
  prep_all<<<dim3(3584), blk256, 0, stream>>>(x, xh, W_in, WinT, W1, W1T,
                                              W2, W2T, W_out, WoutT);

  dim3 blk512(512);
  const dim3 g1024(256);           // 1024x1024 out: 16 m x 16 n 64x64 tiles
  const dim3 g512 (128);           // 1024x512  out: 16 m x  8 n tiles

  // z0 = x @ W_in + b_in   (K=512 -> NITER=4)
  gemm64<false, false, 4><<<g1024, blk512, 0, stream>>>(
      xh, WinT, b_in, za, nullptr, 1024, 512);

  // Picard: z <- relu(z@W1+b1)@W2+b2, 6 iterations (K=1024 -> NITER=8)
  _Float16* zc = za;
  _Float16* zn = zb;
  for (int it = 0; it < 6; it++) {
    if (it == 0) {
      // DIAGNOSTIC dispatch: REPEAT=6 recomputes the identical result so
      // this kernel surfaces above the 42us harness fills in rocprof top-5.
      gemm64<true, false, 8, 6><<<g1024, blk512, 0, stream>>>(
          zc, W1T, b1, h, nullptr, 1024, 1024);
    } else {
      gemm64<true, false, 8><<<g1024, blk512, 0, stream>>>(
          zc, W1T, b1, h, nullptr, 1024, 1024);
    }
    gemm64<false, false, 8><<<g1024, blk512, 0, stream>>>(
        h, W2T, b2, zn, nullptr, 1024, 1024);
    _Float16* t = zc; zc = zn; zn = t;
  }

  // out = z* @ W_out + b_out (fp32)
  gemm64<false, true, 8><<<g512, blk512, 0, stream>>>(
      zc, WoutT, b_out, nullptr, out, 512, 1024);
}